// Round 13
// baseline (591.673 us; speedup 1.0000x reference)
//
#include <hip/hip_runtime.h>

// ---------------------------------------------------------------------------
// Conformer block, MI355X gfx950. Inputs/outputs fp32; internal activations
// bf16 with fp32 accumulation via bf16 MFMA 16x16x32.
// Round 13: conv is HBM-traffic-bound on B re-reads (520MB FETCH @ 3TB/s).
// Fix: BM=256 / 512-thread blocks (8 waves, same 64x64 wave tile) -> grid
// 512->256 blocks -> B issued bytes halve. Same weight-direct B-in-reg
// pipeline, same vmcnt(6) accounting, XCD-pinned mapping kept.
// ---------------------------------------------------------------------------

typedef __attribute__((ext_vector_type(4))) float f32x4;
typedef __attribute__((ext_vector_type(8))) short short8;
typedef __attribute__((ext_vector_type(4))) short s16x4;

__device__ __forceinline__ float bfs2f(short s) {
  unsigned u = ((unsigned)(unsigned short)s) << 16;
  float f; __builtin_memcpy(&f, &u, 4); return f;
}
__device__ __forceinline__ short f2bfs(float f) {
  unsigned u; __builtin_memcpy(&u, &f, 4);
  u = (u + 0x7FFFu + ((u >> 16) & 1u)) >> 16;   // RNE
  return (short)u;
}
__device__ __forceinline__ float sigmoidf_(float x) { return 1.f / (1.f + __expf(-x)); }

#define GLOADLDS(gsrc, ldst) \
  __builtin_amdgcn_global_load_lds((__attribute__((address_space(1))) void*)(gsrc), \
                                   (__attribute__((address_space(3))) void*)(ldst), 16, 0, 0)

#define VMCNT_ASM(n) asm volatile("s_waitcnt vmcnt(" #n ")" ::: "memory")
template<int N> __device__ __forceinline__ void vmcnt_wait() {
  if      constexpr (N == 0)  VMCNT_ASM(0);
  else if constexpr (N == 2)  VMCNT_ASM(2);
  else if constexpr (N == 3)  VMCNT_ASM(3);
  else if constexpr (N == 4)  VMCNT_ASM(4);
  else if constexpr (N == 6)  VMCNT_ASM(6);
  else if constexpr (N == 8)  VMCNT_ASM(8);
  else                        VMCNT_ASM(0);
}
#define MEMFENCE asm volatile("" ::: "memory")

enum { EPI_SILU = 0, EPI_F32BIAS = 1, EPI_RES = 2, EPI_QKV = 3, EPI_F32 = 6 };

// ---------------------------------------------------------------------------
// Generic GEMM: C[M,N] = A[M,K] * BT[N,K]^T, bf16 in, fp32 accum. BK=32.
// Triple-buffered; counted vmcnt(L) + RAW s_barrier. Last-z K decrement.
// ---------------------------------------------------------------------------
template<int BM, int BN, int WM, int WN, int EPI>
__global__ __launch_bounds__(256) void gemm_bt(
    const short* __restrict__ A, int lda, long zAh, long zAl,
    const short* __restrict__ BT, int ldbt, long zBh, long zBl,
    int K, int Kdec,
    void* C, int ldc, long zCh, long zCl, int zdiv,
    const float* bias, const float* bias2, const float* bias3,
    const float* resid, float alpha, float beta)
{
  constexpr int FM = BM / (WM * 16), FN = BN / (WN * 16);
  constexpr int AIT = (BM * 4) / 256, BIT = (BN * 4) / 256;
  constexpr int L = AIT + BIT;
  __shared__ short sA[3][BM * 32];
  __shared__ short sB[3][BN * 32];
  const int tid = threadIdx.x;
  const int zmask = (1 << zdiv) - 1;
  const int zhi = (int)(blockIdx.z >> zdiv);
  const int zlo = (int)(blockIdx.z & zmask);
  A  += (long)zhi * zAh + (long)zlo * zAl;
  BT += (long)zhi * zBh + (long)zlo * zBl;
  char* cbase = (char*)C + (long)zhi * zCh + (long)zlo * zCl;
  const int m0 = blockIdx.x * BM, n0 = blockIdx.y * BN;
  const int Keff = K - (zlo == zmask ? Kdec : 0);

  auto stage = [&](int buf, int k0) {
#pragma unroll
    for (int it = 0; it < AIT; ++it) {
      int idx = it * 256 + tid;
      GLOADLDS(A + (long)(m0 + (idx >> 2)) * lda + k0 + (idx & 3) * 8, &sA[buf][idx * 8]);
    }
#pragma unroll
    for (int it = 0; it < BIT; ++it) {
      int idx = it * 256 + tid;
      GLOADLDS(BT + (long)(n0 + (idx >> 2)) * ldbt + k0 + (idx & 3) * 8, &sB[buf][idx * 8]);
    }
  };

  f32x4 acc[FM][FN];
#pragma unroll
  for (int i = 0; i < FM; ++i) {
#pragma unroll
    for (int j = 0; j < FN; ++j) acc[i][j] = (f32x4){0.f, 0.f, 0.f, 0.f};
  }
  const int lane = tid & 63, wid = tid >> 6;
  const int wm = wid / WN, wn = wid % WN;
  const int lr = lane & 15, kg = lane >> 4;
  const int aRow = wm * (BM / WM), bRow = wn * (BN / WN);

  const int nt = Keff >> 5;
  stage(0, 0);
  stage(1, 32);
  vmcnt_wait<L>();
  __builtin_amdgcn_s_barrier();

  int cur = 0, sbuf = 2;
  for (int t = 0; t < nt; ++t) {
    const bool st = (t + 2 < nt);
    if (st) stage(sbuf, (t + 2) * 32);
    short8 af[FM], bfr[FN];
#pragma unroll
    for (int mi = 0; mi < FM; ++mi)
      af[mi] = *(const short8*)&sA[cur][(aRow + mi * 16 + lr) * 32 + kg * 8];
#pragma unroll
    for (int ni = 0; ni < FN; ++ni)
      bfr[ni] = *(const short8*)&sB[cur][(bRow + ni * 16 + lr) * 32 + kg * 8];
#pragma unroll
    for (int mi = 0; mi < FM; ++mi) {
#pragma unroll
      for (int ni = 0; ni < FN; ++ni)
        acc[mi][ni] = __builtin_amdgcn_mfma_f32_16x16x32_bf16(af[mi], bfr[ni], acc[mi][ni], 0, 0, 0);
    }
    if (st) vmcnt_wait<L>(); else vmcnt_wait<0>();
    __builtin_amdgcn_s_barrier();
    cur = (cur == 2) ? 0 : cur + 1;
    sbuf = (sbuf == 2) ? 0 : sbuf + 1;
  }

  const int baseRow = m0 + aRow, baseCol = n0 + bRow;
#pragma unroll
  for (int mi = 0; mi < FM; ++mi) {
#pragma unroll
    for (int ni = 0; ni < FN; ++ni) {
      const int col = baseCol + ni * 16 + lr;
#pragma unroll
      for (int r = 0; r < 4; ++r) {
        const int row = baseRow + mi * 16 + kg * 4 + r;
        float v = acc[mi][ni][r];
        if (EPI == EPI_SILU) {
          v += bias[col];
          v = v * sigmoidf_(v);
          ((short*)cbase)[(long)row * ldc + col] = f2bfs(v);
        } else if (EPI == EPI_F32BIAS) {
          v += bias[col];
          ((float*)cbase)[(long)row * ldc + col] = v;
        } else if (EPI == EPI_RES) {
          v += bias[col];
          float rv = resid[(long)row * ldc + col];
          ((float*)cbase)[(long)row * ldc + col] = alpha * rv + beta * v;
        } else if (EPI == EPI_QKV) {
          if (col < 512)       v = (v + bias[col]) * 0.125f;   // fold 1/sqrt(64) into q
          else if (col < 1024) v += bias2[col - 512];
          else                 v += bias3[col - 1024];
          ((short*)cbase)[(long)row * ldc + col] = f2bfs(v);
        } else if (EPI == EPI_F32) {
          ((float*)cbase)[(long)row * ldc + col] = v;
        }
      }
    }
  }
}

// ---------------------------------------------------------------------------
// Conv, weight-direct, BM=256 / 512 threads (8 waves, 4m x 2n, wave 64x64).
// A staged in LDS (3 x 16KB), B global->reg from fragment-packed wdP with
// 1-iter prefetch. 2-way split-K, XCD-pinned flat grid 256 (bid&7 -> (y,kg);
// bid>>3 -> (x = j&3, b = j>>2)). K=8192 (kg=0) / 7680 (kg=1).
// ---------------------------------------------------------------------------
__global__ __launch_bounds__(512) void conv_direct2(
    const short* __restrict__ Abase,   // glu_pad + 512 (t0+1 row offset)
    const short* __restrict__ wdP,     // [rowtile=32][chunk=496][512]
    float* __restrict__ parts)
{
  __shared__ short sA[3][256 * 32];
  const int tid = threadIdx.x;
  const int bid = blockIdx.x;
  const int cc = bid & 7, j = bid >> 3;
  const int y = cc >> 1, kg = cc & 1;
  const int x = j & 3, b = j >> 2;
  const int m0 = x * 256, n0 = y * 128;
  const short* A = Abase + (long)b * (1056 * 512) + kg * 8192;
  float* cbase = parts + (long)kg * (8192L * 512) + (long)b * (1024L * 512);
  const int nt = kg ? 240 : 256;   // even

  const int lane = tid & 63, wid = tid >> 6;
  const int wm = wid >> 1, wn = wid & 1;
  const int lr = lane & 15, kgr = lane >> 4;
  const int aRow = wm * 64, bRow = wn * 64;

  const short* Bp = wdP + (long)((n0 + bRow) >> 4) * (496L * 512)
                        + (long)(kg * 256) * 512 + lane * 8;

  auto stageA = [&](int buf, int t) {
    const int k0 = t * 32;
#pragma unroll
    for (int it = 0; it < 2; ++it) {
      int idx = it * 512 + tid;
      GLOADLDS(A + (long)(m0 + (idx >> 2)) * 512 + k0 + (idx & 3) * 8, &sA[buf][idx * 8]);
    }
  };

  f32x4 acc[4][4];
#pragma unroll
  for (int i = 0; i < 4; ++i) {
#pragma unroll
    for (int jj = 0; jj < 4; ++jj) acc[i][jj] = (f32x4){0.f, 0.f, 0.f, 0.f};
  }
  short8 b0[4], b1[4];

  stageA(0, 0);
  stageA(1, 1);
  MEMFENCE;
#pragma unroll
  for (int ni = 0; ni < 4; ++ni)
    b0[ni] = *(const short8*)(Bp + ni * (496L * 512));
  MEMFENCE;
  vmcnt_wait<4>();              // Ast(0),Ast(1) done; b0 may be in flight
  __builtin_amdgcn_s_barrier();

  int rd = 0;                   // buf holding tile t
  for (int t = 0; t < nt; t += 2) {
    // ---- phase 0: compute t (b0), prefetch B(t+1)->b1, stage A(t+2) ----
    {
      int wr = rd - 1; if (wr < 0) wr += 3;      // (rd+2)%3
      stageA(wr, t + 2);
      MEMFENCE;
#pragma unroll
      for (int ni = 0; ni < 4; ++ni)
        b1[ni] = *(const short8*)(Bp + (long)(t + 1) * 512 + ni * (496L * 512));
      MEMFENCE;
      short8 af[4];
#pragma unroll
      for (int mi = 0; mi < 4; ++mi)
        af[mi] = *(const short8*)&sA[rd][(aRow + mi * 16 + lr) * 32 + kgr * 8];
#pragma unroll
      for (int mi = 0; mi < 4; ++mi) {
#pragma unroll
        for (int ni = 0; ni < 4; ++ni)
          acc[mi][ni] = __builtin_amdgcn_mfma_f32_16x16x32_bf16(af[mi], b0[ni], acc[mi][ni], 0, 0, 0);
      }
      vmcnt_wait<6>();          // all but {Ast(t+2)x2, B(t+1)x4}: A(t+1) resident
      __builtin_amdgcn_s_barrier();
      rd = (rd == 2) ? 0 : rd + 1;
    }
    // ---- phase 1: compute t+1 (b1), prefetch B(t+2)->b0, stage A(t+3) ----
    {
      int wr = rd - 1; if (wr < 0) wr += 3;
      stageA(wr, t + 3);
      MEMFENCE;
#pragma unroll
      for (int ni = 0; ni < 4; ++ni)
        b0[ni] = *(const short8*)(Bp + (long)(t + 2) * 512 + ni * (496L * 512));
      MEMFENCE;
      short8 af[4];
#pragma unroll
      for (int mi = 0; mi < 4; ++mi)
        af[mi] = *(const short8*)&sA[rd][(aRow + mi * 16 + lr) * 32 + kgr * 8];
#pragma unroll
      for (int mi = 0; mi < 4; ++mi) {
#pragma unroll
        for (int ni = 0; ni < 4; ++ni)
          acc[mi][ni] = __builtin_amdgcn_mfma_f32_16x16x32_bf16(af[mi], b1[ni], acc[mi][ni], 0, 0, 0);
      }
      vmcnt_wait<6>();
      __builtin_amdgcn_s_barrier();
      rd = (rd == 2) ? 0 : rd + 1;
    }
  }
  vmcnt_wait<0>();

  const int baseRow = m0 + aRow, baseCol = n0 + bRow;
#pragma unroll
  for (int mi = 0; mi < 4; ++mi) {
#pragma unroll
    for (int ni = 0; ni < 4; ++ni) {
      const int col = baseCol + ni * 16 + lr;
#pragma unroll
      for (int r = 0; r < 4; ++r) {
        const int row = baseRow + mi * 16 + kgr * 4 + r;
        cbase[(long)row * 512 + col] = acc[mi][ni][r];
      }
    }
  }
}

// ---------------------------------------------------------------------------
// Flash attention (round 10). Block = 64 q-rows of one (b,h); 4 waves.
// ---------------------------------------------------------------------------
__global__ __launch_bounds__(256) void flash_attn(
    const short* __restrict__ qkv,   // [b][t][1536], q pre-scaled by 1/8
    const short* __restrict__ vt,    // [(b*8+h)][e=64][t=1024]
    short* __restrict__ out)         // scrambled: [b][n>>3][(n&7)*64+e]
{
  __shared__ short sQ[64 * 64];
  __shared__ short sK[64 * 64];
  __shared__ short sV[64 * 64];
  __shared__ short sP[4][16 * 64];
  const int tid = threadIdx.x;
  const int lane = tid & 63, w = tid >> 6;
  const int lr = lane & 15, kg = lane >> 4;
  const int bh = (int)blockIdx.z;
  const int b = bh >> 3, h = bh & 7;
  const int q0 = blockIdx.x * 64;
  const short* qbase = qkv + (long)b * 1024 * 1536 + h * 64;
  const short* kbase = qbase + 512;
  const short* vtb = vt + (long)bh * 65536;

#pragma unroll
  for (int it = 0; it < 2; ++it) {
    int idx = it * 256 + tid;
    int row = idx >> 3, c = (idx & 7) ^ (row & 7);
    GLOADLDS(qbase + (long)(q0 + row) * 1536 + c * 8, &sQ[idx * 8]);
  }
  __syncthreads();
  short8 bq[2];
#pragma unroll
  for (int ks = 0; ks < 2; ++ks)
    bq[ks] = *(const short8*)&sQ[(w * 16 + lr) * 64 + ((ks * 4 + kg) ^ (lr & 7)) * 8];

  f32x4 po[4];
#pragma unroll
  for (int mi = 0; mi < 4; ++mi) po[mi] = (f32x4){0.f, 0.f, 0.f, 0.f};
  float m = -3.0e38f, l = 0.f;

  for (int s0 = 0; s0 < 1024; s0 += 64) {
#pragma unroll
    for (int it = 0; it < 2; ++it) {
      int idx = it * 256 + tid;
      int row = idx >> 3, c = (idx & 7) ^ (row & 7);
      GLOADLDS(kbase + (long)(s0 + row) * 1536 + c * 8, &sK[idx * 8]);
    }
#pragma unroll
    for (int it = 0; it < 2; ++it) {
      int idx = it * 256 + tid;
      int row = idx >> 3, c = (idx & 7) ^ (row & 7);
      GLOADLDS(vtb + (long)row * 1024 + s0 + c * 8, &sV[idx * 8]);
    }
    __syncthreads();

    f32x4 as[4];
#pragma unroll
    for (int mi = 0; mi < 4; ++mi) as[mi] = (f32x4){0.f, 0.f, 0.f, 0.f};
#pragma unroll
    for (int ks = 0; ks < 2; ++ks) {
#pragma unroll
      for (int mi = 0; mi < 4; ++mi) {
        short8 ak = *(const short8*)&sK[(mi * 16 + lr) * 64 + ((ks * 4 + kg) ^ (lr & 7)) * 8];
        as[mi] = __builtin_amdgcn_mfma_f32_16x16x32_bf16(ak, bq[ks], as[mi], 0, 0, 0);
      }
    }

    float rmax = as[0][0];
#pragma unroll
    for (int mi = 0; mi < 4; ++mi) {
#pragma unroll
      for (int r = 0; r < 4; ++r) rmax = fmaxf(rmax, as[mi][r]);
    }
    rmax = fmaxf(rmax, __shfl_xor(rmax, 16));
    rmax = fmaxf(rmax, __shfl_xor(rmax, 32));
    const float mn = fmaxf(m, rmax);
    const float sc = __expf(m - mn);
    float p[4][4];
    float rsum = 0.f;
#pragma unroll
    for (int mi = 0; mi < 4; ++mi) {
#pragma unroll
      for (int r = 0; r < 4; ++r) { p[mi][r] = __expf(as[mi][r] - mn); rsum += p[mi][r]; }
    }
    rsum += __shfl_xor(rsum, 16);
    rsum += __shfl_xor(rsum, 32);
    l = l * sc + rsum;
    m = mn;
#pragma unroll
    for (int mi = 0; mi < 4; ++mi) {
#pragma unroll
      for (int r = 0; r < 4; ++r) po[mi][r] *= sc;
    }
#pragma unroll
    for (int mi = 0; mi < 4; ++mi) {
      s16x4 pk;
#pragma unroll
      for (int r = 0; r < 4; ++r) pk[r] = f2bfs(p[mi][r]);
      *(s16x4*)&sP[w][lr * 64 + ((mi ^ (lr & 3)) * 16 + kg * 4)] = pk;
    }
#pragma unroll
    for (int ks = 0; ks < 2; ++ks) {
      short8 bp = *(const short8*)&sP[w][lr * 64 + (((ks * 2 + (kg >> 1)) ^ (lr & 3)) * 16 + (kg & 1) * 8)];
#pragma unroll
      for (int mi = 0; mi < 4; ++mi) {
        short8 av = *(const short8*)&sV[(mi * 16 + lr) * 64 + ((ks * 4 + kg) ^ (lr & 7)) * 8];
        po[mi] = __builtin_amdgcn_mfma_f32_16x16x32_bf16(av, bp, po[mi], 0, 0, 0);
      }
    }
    __syncthreads();
  }

  const float inv = 1.f / l;
  const int t2 = q0 + w * 16 + lr;
  const int n = h * 1024 + t2;
  short* ob = out + ((long)b * 1024 + (n >> 3)) * 512 + (n & 7) * 64;
#pragma unroll
  for (int mi = 0; mi < 4; ++mi) {
    s16x4 o;
#pragma unroll
    for (int r = 0; r < 4; ++r) o[r] = f2bfs(po[mi][r] * inv);
    *(s16x4*)&ob[mi * 16 + kg * 4] = o;
  }
}

// ---------------------------------------------------------------------------
// Sum TWO conv split-K partials -> z bf16, accumulate BN sum/sumsq stats.
// ---------------------------------------------------------------------------
__global__ __launch_bounds__(256) void reduce_bn(
    const float* __restrict__ parts, long pstride,
    short* __restrict__ z, float* stats)
{
  const int r0 = blockIdx.x * 16;
  const int c = threadIdx.x * 2;
  float s0 = 0.f, s1 = 0.f, q0 = 0.f, q1 = 0.f;
#pragma unroll 4
  for (int r = 0; r < 16; ++r) {
    const long idx = (long)(r0 + r) * 512 + c;
    float a0 = parts[idx] + parts[idx + pstride];
    float a1 = parts[idx + 1] + parts[idx + 1 + pstride];
    z[idx] = f2bfs(a0); z[idx + 1] = f2bfs(a1);
    s0 += a0; s1 += a1; q0 += a0 * a0; q1 += a1 * a1;
  }
  atomicAdd(&stats[c], s0);
  atomicAdd(&stats[c + 1], s1);
  atomicAdd(&stats[512 + c], q0);
  atomicAdd(&stats[512 + c + 1], q1);
}

// ---------------------------------------------------------------------------
// LayerNorm rows of 512 (fp32 in), one wave per row (4 rows/block).
// ---------------------------------------------------------------------------
template<int ADDPE, int OUTF32>
__global__ __launch_bounds__(256) void ln_rows(
    const float* __restrict__ X, const float* __restrict__ g, const float* __restrict__ b,
    const float* __restrict__ pe, void* __restrict__ Y)
{
  const int row = blockIdx.x * 4 + (threadIdx.x >> 6);
  const int lane = threadIdx.x & 63;
  const int c0 = lane * 8;
  const float* src = X + (long)row * 512 + c0;
  f32x4 a = *(const f32x4*)src, c = *(const f32x4*)(src + 4);
  float x[8] = {a[0], a[1], a[2], a[3], c[0], c[1], c[2], c[3]};
  float s = 0.f, q = 0.f;
#pragma unroll
  for (int j = 0; j < 8; ++j) { s += x[j]; q += x[j] * x[j]; }
#pragma unroll
  for (int off = 32; off > 0; off >>= 1) { s += __shfl_xor(s, off); q += __shfl_xor(q, off); }
  const float mean = s * (1.f / 512.f);
  const float var = q * (1.f / 512.f) - mean * mean;
  const float rstd = rsqrtf(var + 1e-5f);
  f32x4 g0 = *(const f32x4*)(g + c0), g1 = *(const f32x4*)(g + c0 + 4);
  f32x4 b0 = *(const f32x4*)(b + c0), b1 = *(const f32x4*)(b + c0 + 4);
  float gg[8] = {g0[0], g0[1], g0[2], g0[3], g1[0], g1[1], g1[2], g1[3]};
  float bb[8] = {b0[0], b0[1], b0[2], b0[3], b1[0], b1[1], b1[2], b1[3]};
  float y[8];
#pragma unroll
  for (int j = 0; j < 8; ++j) {
    y[j] = (x[j] - mean) * rstd * gg[j] + bb[j];
    if (ADDPE) y[j] += pe[(long)(row & 1023) * 512 + c0 + j];
  }
  if (OUTF32) {
    float* dst = (float*)Y + (long)row * 512 + c0;
    *(f32x4*)dst = (f32x4){y[0], y[1], y[2], y[3]};
    *(f32x4*)(dst + 4) = (f32x4){y[4], y[5], y[6], y[7]};
  } else {
    short8 o;
#pragma unroll
    for (int j = 0; j < 8; ++j) o[j] = f2bfs(y[j]);
    *(short8*)((short*)Y + (long)row * 512 + c0) = o;
  }
}

// ---------------------------------------------------------------------------
// 64x64-tile transpose -> bf16 out. INF32: fp32 input (weights) or bf16 input.
// ---------------------------------------------------------------------------
template<int INF32>
__global__ __launch_bounds__(256) void transpose64(
    const void* __restrict__ in_, int ldin, short* __restrict__ out, int ldout,
    int ctiles, int zshift, long zh_in, long zl_in, long z_out)
{
  __shared__ short t[64][72];
  const int z = blockIdx.z;
  const long inoff = (long)(z >> zshift) * zh_in + (long)(z & ((1 << zshift) - 1)) * zl_in;
  const int tr = blockIdx.x / ctiles, tc = blockIdx.x % ctiles;
  short* dst = out + (long)z * z_out + (long)(tc * 64) * ldout + tr * 64;
  const int tid = threadIdx.x;
#pragma unroll
  for (int p = 0; p < 2; ++p) {
    int idx = p * 256 + tid;
    int r = idx >> 3, c8 = (idx & 7) * 8;
    if (INF32) {
      const float* src = (const float*)in_ + inoff + (long)(tr * 64 + r) * ldin + tc * 64 + c8;
      f32x4 v0 = *(const f32x4*)src, v1 = *(const f32x4*)(src + 4);
#pragma unroll
      for (int j = 0; j < 4; ++j) { t[r][c8 + j] = f2bfs(v0[j]); t[r][c8 + 4 + j] = f2bfs(v1[j]); }
    } else {
      const short* src = (const short*)in_ + inoff + (long)(tr * 64 + r) * ldin + tc * 64 + c8;
      short8 v = *(const short8*)src;
#pragma unroll
      for (int j = 0; j < 8; ++j) t[r][c8 + j] = v[j];
    }
  }
  __syncthreads();
#pragma unroll
  for (int p = 0; p < 2; ++p) {
    int idx = p * 256 + tid;
    int c = idx >> 3, r8 = (idx & 7) * 8;
    short8 v;
#pragma unroll
    for (int j = 0; j < 8; ++j) v[j] = t[r8 + j][c];
    *(short8*)(dst + (long)c * ldout + r8) = v;
  }
}

// wdP fragment-packed: value wd[e][i][kk] (flat k = kk*512+i) ->
// wdP[((e>>4)*496 + (k>>5))*512 + ((k>>3)&3)*128 + (e&15)*8 + (k&7)]
__global__ __launch_bounds__(256) void wd_pack(const float* __restrict__ wd, short* __restrict__ wdP)
{
  const int gid = blockIdx.x * 256 + threadIdx.x;  // 262144 = 512*512
  const int e = gid >> 9, i = gid & 511;
  const float* src = wd + ((long)e * 512 + i) * 31;
  const long rowtile = (long)(e >> 4) * (496L * 512);
  const int r8 = (e & 15) * 8;
#pragma unroll
  for (int kk = 0; kk < 31; ++kk) {
    const int k = kk * 512 + i;
    wdP[rowtile + (long)(k >> 5) * 512 + ((k >> 3) & 3) * 128 + r8 + (k & 7)] = f2bfs(src[kk]);
  }
}

// pe[t][2p] = sin(t * 10000^(-p/256)), pe[t][2p+1] = cos(...)
__global__ __launch_bounds__(256) void pe_init(float* __restrict__ pe)
{
  const int gid = blockIdx.x * 256 + threadIdx.x;  // 262144 = 1024*256
  const int t = gid >> 8, p = gid & 255;
  const float freq = __expf(-(float)p * (9.210340371976184f / 256.f));
  const float ang = (float)t * freq;
  pe[(long)t * 512 + 2 * p]     = sinf(ang);
  pe[(long)t * 512 + 2 * p + 1] = cosf(ang);
}

// glu = a * sigmoid(g) from y1[N][1024] fp32 -> glu_pad[b][16+t][512] bf16
__global__ __launch_bounds__(256) void glu_kernel(const float* __restrict__ y1, short* __restrict__ gp)
{
  const int gid = blockIdx.x * 256 + threadIdx.x;  // 1048576
  const int row = gid >> 7;
  const int ci = (gid & 127) * 4;
  const float* base = y1 + (long)row * 1024;
  f32x4 a = *(const f32x4*)(base + ci);
  f32x4 g = *(const f32x4*)(base + 512 + ci);
  const int b = row >> 10, t = row & 1023;
  s16x4 o;
#pragma unroll
  for (int j = 0; j < 4; ++j) o[j] = f2bfs(a[j] * sigmoidf_(g[j]));
  *(s16x4*)(gp + ((long)b * 1056 + 16 + t) * 512 + ci) = o;
}

__global__ void bn_stats(float* stats, const float* __restrict__ bn_g, const float* __restrict__ bn_b)
{
  const int c = blockIdx.x * 256 + threadIdx.x;
  if (c < 512) {
    float mean = stats[c] * (1.f / 8192.f);
    float var = stats[512 + c] * (1.f / 8192.f) - mean * mean;
    float sc = bn_g[c] * rsqrtf(var + 1e-5f);
    stats[1024 + c] = sc;
    stats[1536 + c] = bn_b[c] - mean * sc;
  }
}

__global__ __launch_bounds__(256) void bn_silu(const short* __restrict__ z, const float* __restrict__ stats,
                                               short* __restrict__ out)
{
  const long base = ((long)blockIdx.x * 256 + threadIdx.x) * 8;
  const int c0 = (int)(base & 511);
  short8 v = *(const short8*)(z + base);
  short8 o;
#pragma unroll
  for (int j = 0; j < 8; ++j) {
    const int c = c0 + j;
    float y = bfs2f(v[j]) * stats[1024 + c] + stats[1536 + c];
    o[j] = f2bfs(y * sigmoidf_(y));
  }
  *(short8*)(out + base) = o;
}

// plain elementwise fp32 -> bf16 cast (grid-stride)
__global__ __launch_bounds__(256) void cast_bf16(const float* __restrict__ in, short* __restrict__ out, long n)
{
  for (long i = (long)blockIdx.x * 256 + threadIdx.x; i < n; i += (long)gridDim.x * 256)
    out[i] = f2bfs(in[i]);
}

// ---------------------------------------------------------------------------
extern "C" void kernel_launch(void* const* d_in, const int* in_sizes, int n_in,
                              void* d_out, int out_size, void* d_ws, size_t ws_size,
                              hipStream_t stream)
{
  (void)in_sizes; (void)n_in; (void)out_size; (void)ws_size;
  const float* x_in   = (const float*)d_in[0];
  const float* ff1_g  = (const float*)d_in[1];
  const float* ff1_bb = (const float*)d_in[2];
  const float* ff1_w1 = (const float*)d_in[3];
  const float* ff1_b1 = (const float*)d_in[4];
  const float* ff1_w2 = (const float*)d_in[5];
  const float* ff1_b2 = (const float*)d_in[6];
  const float* mha_g  = (const float*)d_in[7];
  const float* mha_b  = (const float*)d_in[8];
  const float* wq     = (const float*)d_in[9];
  const float* bq     = (const float*)d_in[10];
  const float* wk     = (const float*)d_in[11];
  const float* bk     = (const float*)d_in[12];
  const float* wv     = (const float*)d_in[13];
  const float* bv     = (const float*)d_in[14];
  const float* wo     = (const float*)d_in[15];
  const float* bo     = (const float*)d_in[16];
  const float* cv_g   = (const float*)d_in[17];
  const float* cv_b   = (const float*)d_in[18];
  const float* cv_w1  = (const float*)d_in[19];
  const float* cv_b1  = (const float*)d_in[20];
  const float* cv_wd  = (const float*)d_in[21];
  const float* bn_g   = (const float*)d_in[22];
  const float* bn_b   = (const float*)d_in[23];
  const float* cv_w2  = (const float*)d_in[24];
  const float* cv_b2  = (const float*)d_in[25];
  const float* ff2_g  = (const float*)d_in[26];
  const float* ff2_b  = (const float*)d_in[27];
  const float* ff2_w1 = (const float*)d_in[28];
  const float* ff2_b1 = (const float*)d_in[29];
  const float* ff2_w2 = (const float*)d_in[30];
  const float* ff2_b2 = (const float*)d_in[31];
  const float* fin_g  = (const float*)d_in[32];
  const float* fin_b  = (const float*)d_in[33];

  size_t off = 0;
  char* wsb = (char*)d_ws;
  auto take = [&](size_t n) { char* p = wsb + off; off += (n + 255) & ~(size_t)255; return p; };
  short* ff1w1T = (short*)take(2048L * 512 * 2);
  short* ff1w2T = (short*)take(512L * 2048 * 2);
  short* qkvT   = (short*)take(1536L * 512 * 2);
  short* woT    = (short*)take(512L * 512 * 2);
  short* cw1b   = (short*)take(1024L * 512 * 2);
  short* cw2b   = (short*)take(512L * 512 * 2);
  short* wdP    = (short*)take(512L * 15872 * 2);
  short* ff2w1T = (short*)take(2048L * 512 * 2);
  short* ff2w2T = (short*)take(512L * 2048 * 2);
  float* xcur   = (float*)take(8192L * 512 * 4);
  char*  Ra     = take(8192L * 2048 * 2);            // hid bf16 / qkv bf16 / y1 fp32
  short* Rb     = (short*)take(8192L * 512 * 2);     // ln out / att_o / conv z
  short* Rg     = (short*)take(8L * 1056 * 512 * 2); // glu_pad / bn act
  char*  Rshare = take(2L * 8192 * 512 * 4);         // conv partials x2 (32MB)
  short* vt     = (short*)take(64L * 64 * 1024 * 2); // V^T per (b,h)
  float* pe     = (float*)take(1024L * 512 * 4);
  float* stats  = (float*)take(2048L * 4);

  short* hid = (short*)Ra;
  short* qkv = (short*)Ra;
  float* y1  = (float*)Ra;
  float* part0 = (float*)Rshare;

  // ---- weight packs (fp32 -> bf16; per call) ----
  transpose64<1><<<dim3(256, 1, 1), 256, 0, stream>>>(ff1_w1, 2048, ff1w1T, 512, 32, 0, 0, 0, 0);
  transpose64<1><<<dim3(256, 1, 1), 256, 0, stream>>>(ff1_w2, 512, ff1w2T, 2048, 8, 0, 0, 0, 0);
  transpose64<1><<<dim3(8, 1, 8), 256, 0, stream>>>(wq, 64, qkvT, 512, 1, 0, 32768, 0, 32768);
  transpose64<1><<<dim3(8, 1, 8), 256, 0, stream>>>(wk, 64, qkvT + 512 * 512, 512, 1, 0, 32768, 0, 32768);
  transpose64<1><<<dim3(8, 1, 8), 256, 0, stream>>>(wv, 64, qkvT + 1024 * 512, 512, 1, 0, 32768, 0, 32768);
  transpose64<1><<<dim3(64, 1, 1), 256, 0, stream>>>(wo, 512, woT, 512, 8, 0, 0, 0, 0);
  transpose64<1><<<dim3(256, 1, 1), 256, 0, stream>>>(ff2_w1, 2048, ff2w1T, 512, 32, 0, 0, 0, 0);
  transpose64<1><<<dim3(256, 1, 1), 256, 0, stream>>>(ff2_w2, 512, ff2w2T, 2048, 8, 0, 0, 0, 0);
  wd_pack<<<1024, 256, 0, stream>>>(cv_wd, wdP);
  pe_init<<<1024, 256, 0, stream>>>(pe);
  cast_bf16<<<2048, 256, 0, stream>>>(cv_w1, cw1b, 524288L);
  cast_bf16<<<1024, 256, 0, stream>>>(cv_w2, cw2b, 262144L);

  // ---- FF1: x1 = 1.5 x + 0.5 (silu(ln(x) W1 + b1) W2 + b2) ----
  ln_rows<0, 0><<<2048, 256, 0, stream>>>(x_in, ff1_g, ff1_bb, nullptr, Rb);
  gemm_bt<128, 128, 2, 2, EPI_SILU><<<dim3(64, 16, 1), 256, 0, stream>>>(
      Rb, 512, 0, 0, ff1w1T, 512, 0, 0, 512, 0,
      hid, 2048, 0, 0, 0, ff1_b1, nullptr, nullptr, nullptr, 0.f, 0.f);
  gemm_bt<64, 64, 2, 2, EPI_RES><<<dim3(128, 8, 1), 256, 0, stream>>>(
      hid, 2048, 0, 0, ff1w2T, 2048, 0, 0, 2048, 0,
      xcur, 512, 0, 0, 0, ff1_b2, nullptr, nullptr, x_in, 1.5f, 0.5f);

  // ---- MHSA: x2 = 2 x1 + (scramble(attn) Wo + bo) ----
  ln_rows<1, 0><<<2048, 256, 0, stream>>>(xcur, mha_g, mha_b, pe, Rb);
  gemm_bt<128, 128, 2, 2, EPI_QKV><<<dim3(64, 12, 1), 256, 0, stream>>>(
      Rb, 512, 0, 0, qkvT, 512, 0, 0, 512, 0,
      qkv, 1536, 0, 0, 0, bq, bk, bv, nullptr, 0.f, 0.f);
  transpose64<0><<<dim3(16, 1, 64), 256, 0, stream>>>(qkv + 1024, 1536, vt, 1024, 1, 3,
                                                      1024L * 1536, 64, 65536);
  flash_attn<<<dim3(16, 1, 64), 256, 0, stream>>>(qkv, vt, Rb);
  gemm_bt<64, 64, 2, 2, EPI_RES><<<dim3(128, 8, 1), 256, 0, stream>>>(
      Rb, 512, 0, 0, woT, 512, 0, 0, 512, 0,
      xcur, 512, 0, 0, 0, bo, nullptr, nullptr, xcur, 2.f, 1.f);

  // ---- Conv module: x3 = 2 x2 + (W2 silu(BN(conv(glu(W1 ln(x2) + b1)))) + b2) ----
  ln_rows<0, 0><<<2048, 256, 0, stream>>>(xcur, cv_g, cv_b, nullptr, Rb);
  gemm_bt<128, 128, 2, 2, EPI_F32BIAS><<<dim3(64, 8, 1), 256, 0, stream>>>(
      Rb, 512, 0, 0, cw1b, 512, 0, 0, 512, 0,
      y1, 1024, 0, 0, 0, cv_b1, nullptr, nullptr, nullptr, 0.f, 0.f);
  (void)hipMemsetAsync(Rg, 0, 8L * 1056 * 512 * 2, stream);
  glu_kernel<<<4096, 256, 0, stream>>>(y1, Rg);
  (void)hipMemsetAsync(stats, 0, 1024 * sizeof(float), stream);
  conv_direct2<<<256, 512, 0, stream>>>(Rg + 512, wdP, part0);
  reduce_bn<<<512, 256, 0, stream>>>(part0, 8192L * 512, Rb, stats);
  bn_stats<<<2, 256, 0, stream>>>(stats, bn_g, bn_b);
  bn_silu<<<2048, 256, 0, stream>>>(Rb, stats, (short*)Rg);
  gemm_bt<64, 64, 2, 2, EPI_RES><<<dim3(128, 8, 1), 256, 0, stream>>>(
      (short*)Rg, 512, 0, 0, cw2b, 512, 0, 0, 512, 0,
      xcur, 512, 0, 0, 0, cv_b2, nullptr, nullptr, xcur, 2.f, 1.f);

  // ---- FF2: x4 = 1.5 x3 + 0.5 (...) ----
  ln_rows<0, 0><<<2048, 256, 0, stream>>>(xcur, ff2_g, ff2_b, nullptr, Rb);
  gemm_bt<128, 128, 2, 2, EPI_SILU><<<dim3(64, 16, 1), 256, 0, stream>>>(
      Rb, 512, 0, 0, ff2w1T, 512, 0, 0, 512, 0,
      hid, 2048, 0, 0, 0, ff2_b1, nullptr, nullptr, nullptr, 0.f, 0.f);
  gemm_bt<64, 64, 2, 2, EPI_RES><<<dim3(128, 8, 1), 256, 0, stream>>>(
      hid, 2048, 0, 0, ff2w2T, 2048, 0, 0, 2048, 0,
      xcur, 512, 0, 0, 0, ff2_b2, nullptr, nullptr, xcur, 1.5f, 0.5f);

  // ---- final LN -> d_out (fp32) ----
  ln_rows<0, 1><<<2048, 256, 0, stream>>>(xcur, fin_g, fin_b, nullptr, (float*)d_out);
}

// Round 14
// 547.157 us; speedup vs baseline: 1.0814x; 1.0814x over previous
//
#include <hip/hip_runtime.h>

// ---------------------------------------------------------------------------
// Conformer block, MI355X gfx950. Inputs/outputs fp32; internal activations
// bf16 with fp32 accumulation via bf16 MFMA 16x16x32.
// Round 14: conv A-refetch fix. Flat-K window trick re-read every A byte 16x
// through L2 (1GB issued, block-count invariant -> the 520MB FETCH wall).
// New conv_tap: stage 144-row x 32-i glu slab in LDS ONCE per i-chunk, run
// all 16 taps against it (row-shifted LDS frag reads). A traffic 1GB -> 74MB.
// B weight-direct in regs (unrolled kk ping-pong). wd padded to 32 taps
// (tap 31 = 0) for uniform split-K halves. Rest = round 12 (best).
// ---------------------------------------------------------------------------

typedef __attribute__((ext_vector_type(4))) float f32x4;
typedef __attribute__((ext_vector_type(8))) short short8;
typedef __attribute__((ext_vector_type(4))) short s16x4;

__device__ __forceinline__ float bfs2f(short s) {
  unsigned u = ((unsigned)(unsigned short)s) << 16;
  float f; __builtin_memcpy(&f, &u, 4); return f;
}
__device__ __forceinline__ short f2bfs(float f) {
  unsigned u; __builtin_memcpy(&u, &f, 4);
  u = (u + 0x7FFFu + ((u >> 16) & 1u)) >> 16;   // RNE
  return (short)u;
}
__device__ __forceinline__ float sigmoidf_(float x) { return 1.f / (1.f + __expf(-x)); }

#define GLOADLDS(gsrc, ldst) \
  __builtin_amdgcn_global_load_lds((__attribute__((address_space(1))) void*)(gsrc), \
                                   (__attribute__((address_space(3))) void*)(ldst), 16, 0, 0)

#define VMCNT_ASM(n) asm volatile("s_waitcnt vmcnt(" #n ")" ::: "memory")
template<int N> __device__ __forceinline__ void vmcnt_wait() {
  if      constexpr (N == 0)  VMCNT_ASM(0);
  else if constexpr (N == 2)  VMCNT_ASM(2);
  else if constexpr (N == 3)  VMCNT_ASM(3);
  else if constexpr (N == 4)  VMCNT_ASM(4);
  else if constexpr (N == 6)  VMCNT_ASM(6);
  else if constexpr (N == 8)  VMCNT_ASM(8);
  else                        VMCNT_ASM(0);
}
#define MEMFENCE asm volatile("" ::: "memory")

enum { EPI_SILU = 0, EPI_F32BIAS = 1, EPI_RES = 2, EPI_QKV = 3, EPI_F32 = 6 };

// ---------------------------------------------------------------------------
// Generic GEMM: C[M,N] = A[M,K] * BT[N,K]^T, bf16 in, fp32 accum. BK=32.
// Triple-buffered; counted vmcnt(L) + RAW s_barrier. Last-z K decrement.
// ---------------------------------------------------------------------------
template<int BM, int BN, int WM, int WN, int EPI>
__global__ __launch_bounds__(256) void gemm_bt(
    const short* __restrict__ A, int lda, long zAh, long zAl,
    const short* __restrict__ BT, int ldbt, long zBh, long zBl,
    int K, int Kdec,
    void* C, int ldc, long zCh, long zCl, int zdiv,
    const float* bias, const float* bias2, const float* bias3,
    const float* resid, float alpha, float beta)
{
  constexpr int FM = BM / (WM * 16), FN = BN / (WN * 16);
  constexpr int AIT = (BM * 4) / 256, BIT = (BN * 4) / 256;
  constexpr int L = AIT + BIT;
  __shared__ short sA[3][BM * 32];
  __shared__ short sB[3][BN * 32];
  const int tid = threadIdx.x;
  const int zmask = (1 << zdiv) - 1;
  const int zhi = (int)(blockIdx.z >> zdiv);
  const int zlo = (int)(blockIdx.z & zmask);
  A  += (long)zhi * zAh + (long)zlo * zAl;
  BT += (long)zhi * zBh + (long)zlo * zBl;
  char* cbase = (char*)C + (long)zhi * zCh + (long)zlo * zCl;
  const int m0 = blockIdx.x * BM, n0 = blockIdx.y * BN;
  const int Keff = K - (zlo == zmask ? Kdec : 0);

  auto stage = [&](int buf, int k0) {
#pragma unroll
    for (int it = 0; it < AIT; ++it) {
      int idx = it * 256 + tid;
      GLOADLDS(A + (long)(m0 + (idx >> 2)) * lda + k0 + (idx & 3) * 8, &sA[buf][idx * 8]);
    }
#pragma unroll
    for (int it = 0; it < BIT; ++it) {
      int idx = it * 256 + tid;
      GLOADLDS(BT + (long)(n0 + (idx >> 2)) * ldbt + k0 + (idx & 3) * 8, &sB[buf][idx * 8]);
    }
  };

  f32x4 acc[FM][FN];
#pragma unroll
  for (int i = 0; i < FM; ++i) {
#pragma unroll
    for (int j = 0; j < FN; ++j) acc[i][j] = (f32x4){0.f, 0.f, 0.f, 0.f};
  }
  const int lane = tid & 63, wid = tid >> 6;
  const int wm = wid / WN, wn = wid % WN;
  const int lr = lane & 15, kg = lane >> 4;
  const int aRow = wm * (BM / WM), bRow = wn * (BN / WN);

  const int nt = Keff >> 5;
  stage(0, 0);
  stage(1, 32);
  vmcnt_wait<L>();
  __builtin_amdgcn_s_barrier();

  int cur = 0, sbuf = 2;
  for (int t = 0; t < nt; ++t) {
    const bool st = (t + 2 < nt);
    if (st) stage(sbuf, (t + 2) * 32);
    short8 af[FM], bfr[FN];
#pragma unroll
    for (int mi = 0; mi < FM; ++mi)
      af[mi] = *(const short8*)&sA[cur][(aRow + mi * 16 + lr) * 32 + kg * 8];
#pragma unroll
    for (int ni = 0; ni < FN; ++ni)
      bfr[ni] = *(const short8*)&sB[cur][(bRow + ni * 16 + lr) * 32 + kg * 8];
#pragma unroll
    for (int mi = 0; mi < FM; ++mi) {
#pragma unroll
      for (int ni = 0; ni < FN; ++ni)
        acc[mi][ni] = __builtin_amdgcn_mfma_f32_16x16x32_bf16(af[mi], bfr[ni], acc[mi][ni], 0, 0, 0);
    }
    if (st) vmcnt_wait<L>(); else vmcnt_wait<0>();
    __builtin_amdgcn_s_barrier();
    cur = (cur == 2) ? 0 : cur + 1;
    sbuf = (sbuf == 2) ? 0 : sbuf + 1;
  }

  const int baseRow = m0 + aRow, baseCol = n0 + bRow;
#pragma unroll
  for (int mi = 0; mi < FM; ++mi) {
#pragma unroll
    for (int ni = 0; ni < FN; ++ni) {
      const int col = baseCol + ni * 16 + lr;
#pragma unroll
      for (int r = 0; r < 4; ++r) {
        const int row = baseRow + mi * 16 + kg * 4 + r;
        float v = acc[mi][ni][r];
        if (EPI == EPI_SILU) {
          v += bias[col];
          v = v * sigmoidf_(v);
          ((short*)cbase)[(long)row * ldc + col] = f2bfs(v);
        } else if (EPI == EPI_F32BIAS) {
          v += bias[col];
          ((float*)cbase)[(long)row * ldc + col] = v;
        } else if (EPI == EPI_RES) {
          v += bias[col];
          float rv = resid[(long)row * ldc + col];
          ((float*)cbase)[(long)row * ldc + col] = alpha * rv + beta * v;
        } else if (EPI == EPI_QKV) {
          if (col < 512)       v = (v + bias[col]) * 0.125f;   // fold 1/sqrt(64) into q
          else if (col < 1024) v += bias2[col - 512];
          else                 v += bias3[col - 1024];
          ((short*)cbase)[(long)row * ldc + col] = f2bfs(v);
        } else if (EPI == EPI_F32) {
          ((float*)cbase)[(long)row * ldc + col] = v;
        }
      }
    }
  }
}

// ---------------------------------------------------------------------------
// Conv, tap-tiled: per i-chunk (32 ch), stage 144-row glu slab in LDS once,
// run 16 taps against it (frag row = tap + t-row). A global traffic = 144KB
// per block total. B weight-direct (fragment-packed wdP, 32 taps with tap 31
// zeroed), ping-pong reg prefetch in fully-unrolled kk loop. 2-way split-K,
// XCD-pinned flat grid 512 (bid&7 -> (y,kg); bid>>3 -> (x=j&7, b=j>>3)).
// ---------------------------------------------------------------------------
__global__ __launch_bounds__(256) void conv_tap(
    const short* __restrict__ glu,    // glu_pad base (b stride 1056*512)
    const short* __restrict__ wdP,    // [(e>>4)*512 + chunk][512]
    float* __restrict__ parts)
{
  __shared__ short sA[2][144 * 32];
  const int tid = threadIdx.x;
  const int bid = blockIdx.x;
  const int cc = bid & 7, j = bid >> 3;
  const int y = cc >> 1, kg = cc & 1;
  const int x = j & 7, b = j >> 3;
  const int m0 = x * 128, n0 = y * 128;
  const short* Arow0 = glu + ((long)b * 1056 + m0 + 1 + kg * 16) * 512;
  float* cbase = parts + (long)kg * (8192L * 512) + (long)b * (1024L * 512);

  const int lane = tid & 63, wid = tid >> 6;
  const int wm = wid >> 1, wn = wid & 1;
  const int lr = lane & 15, kgr = lane >> 4;
  const int aRow = wm * 64, bRow = wn * 64;

  const short* Bp = wdP + (long)((n0 + bRow) >> 4) * (512L * 512)
                  + (long)(kg * 256) * 512 + lane * 8;
  const long NSTR = 512L * 512;   // per-16e-rowtile stride

  auto stageA = [&](int buf, int ib) {
#pragma unroll
    for (int it = 0; it < 3; ++it) {
      int idx = it * 256 + tid;
      if (idx < 576) {
        GLOADLDS(Arow0 + (long)(idx >> 2) * 512 + ib * 32 + (idx & 3) * 8,
                 &sA[buf][idx * 8]);
      }
    }
  };

  f32x4 acc[4][4];
#pragma unroll
  for (int i = 0; i < 4; ++i) {
#pragma unroll
    for (int jj = 0; jj < 4; ++jj) acc[i][jj] = (f32x4){0.f, 0.f, 0.f, 0.f};
  }
  short8 b0[4], b1[4];

  stageA(0, 0);
  MEMFENCE;
#pragma unroll
  for (int ni = 0; ni < 4; ++ni)
    b0[ni] = *(const short8*)(Bp + ni * NSTR);
  MEMFENCE;
  vmcnt_wait<4>();              // stage(0) done; b0 may be in flight
  __builtin_amdgcn_s_barrier();

  int cur = 0;
  for (int ib = 0; ib < 16; ++ib) {
    if (ib + 1 < 16) stageA(cur ^ 1, ib + 1);
    MEMFENCE;
#pragma unroll
    for (int kk = 0; kk < 16; ++kk) {
      // prefetch next frag: (kk+1, ib) or (0, ib+1)
      const long noff = (kk + 1 < 16) ? (long)((kk + 1) * 16 + ib) * 512
                                      : (long)(ib + 1) * 512;
      if ((kk & 1) == 0) {
#pragma unroll
        for (int ni = 0; ni < 4; ++ni)
          b1[ni] = *(const short8*)(Bp + noff + ni * NSTR);
      } else {
#pragma unroll
        for (int ni = 0; ni < 4; ++ni)
          b0[ni] = *(const short8*)(Bp + noff + ni * NSTR);
      }
      short8 af[4];
#pragma unroll
      for (int mi = 0; mi < 4; ++mi)
        af[mi] = *(const short8*)&sA[cur][(kk + aRow + mi * 16 + lr) * 32 + kgr * 8];
      if ((kk & 1) == 0) {
#pragma unroll
        for (int mi = 0; mi < 4; ++mi) {
#pragma unroll
          for (int ni = 0; ni < 4; ++ni)
            acc[mi][ni] = __builtin_amdgcn_mfma_f32_16x16x32_bf16(af[mi], b0[ni], acc[mi][ni], 0, 0, 0);
        }
      } else {
#pragma unroll
        for (int mi = 0; mi < 4; ++mi) {
#pragma unroll
          for (int ni = 0; ni < 4; ++ni)
            acc[mi][ni] = __builtin_amdgcn_mfma_f32_16x16x32_bf16(af[mi], b1[ni], acc[mi][ni], 0, 0, 0);
        }
      }
    }
    vmcnt_wait<4>();            // only newest 4 (unconsumed B prefetch) in flight
    __builtin_amdgcn_s_barrier();
    cur ^= 1;
  }
  vmcnt_wait<0>();

  const int baseRow = m0 + aRow, baseCol = n0 + bRow;
#pragma unroll
  for (int mi = 0; mi < 4; ++mi) {
#pragma unroll
    for (int ni = 0; ni < 4; ++ni) {
      const int col = baseCol + ni * 16 + lr;
#pragma unroll
      for (int r = 0; r < 4; ++r) {
        const int row = baseRow + mi * 16 + kgr * 4 + r;
        cbase[(long)row * 512 + col] = acc[mi][ni][r];
      }
    }
  }
}

// ---------------------------------------------------------------------------
// Flash attention (round 10). Block = 64 q-rows of one (b,h); 4 waves.
// ---------------------------------------------------------------------------
__global__ __launch_bounds__(256) void flash_attn(
    const short* __restrict__ qkv,   // [b][t][1536], q pre-scaled by 1/8
    const short* __restrict__ vt,    // [(b*8+h)][e=64][t=1024]
    short* __restrict__ out)         // scrambled: [b][n>>3][(n&7)*64+e]
{
  __shared__ short sQ[64 * 64];
  __shared__ short sK[64 * 64];
  __shared__ short sV[64 * 64];
  __shared__ short sP[4][16 * 64];
  const int tid = threadIdx.x;
  const int lane = tid & 63, w = tid >> 6;
  const int lr = lane & 15, kg = lane >> 4;
  const int bh = (int)blockIdx.z;
  const int b = bh >> 3, h = bh & 7;
  const int q0 = blockIdx.x * 64;
  const short* qbase = qkv + (long)b * 1024 * 1536 + h * 64;
  const short* kbase = qbase + 512;
  const short* vtb = vt + (long)bh * 65536;

#pragma unroll
  for (int it = 0; it < 2; ++it) {
    int idx = it * 256 + tid;
    int row = idx >> 3, c = (idx & 7) ^ (row & 7);
    GLOADLDS(qbase + (long)(q0 + row) * 1536 + c * 8, &sQ[idx * 8]);
  }
  __syncthreads();
  short8 bq[2];
#pragma unroll
  for (int ks = 0; ks < 2; ++ks)
    bq[ks] = *(const short8*)&sQ[(w * 16 + lr) * 64 + ((ks * 4 + kg) ^ (lr & 7)) * 8];

  f32x4 po[4];
#pragma unroll
  for (int mi = 0; mi < 4; ++mi) po[mi] = (f32x4){0.f, 0.f, 0.f, 0.f};
  float m = -3.0e38f, l = 0.f;

  for (int s0 = 0; s0 < 1024; s0 += 64) {
#pragma unroll
    for (int it = 0; it < 2; ++it) {
      int idx = it * 256 + tid;
      int row = idx >> 3, c = (idx & 7) ^ (row & 7);
      GLOADLDS(kbase + (long)(s0 + row) * 1536 + c * 8, &sK[idx * 8]);
    }
#pragma unroll
    for (int it = 0; it < 2; ++it) {
      int idx = it * 256 + tid;
      int row = idx >> 3, c = (idx & 7) ^ (row & 7);
      GLOADLDS(vtb + (long)row * 1024 + s0 + c * 8, &sV[idx * 8]);
    }
    __syncthreads();

    f32x4 as[4];
#pragma unroll
    for (int mi = 0; mi < 4; ++mi) as[mi] = (f32x4){0.f, 0.f, 0.f, 0.f};
#pragma unroll
    for (int ks = 0; ks < 2; ++ks) {
#pragma unroll
      for (int mi = 0; mi < 4; ++mi) {
        short8 ak = *(const short8*)&sK[(mi * 16 + lr) * 64 + ((ks * 4 + kg) ^ (lr & 7)) * 8];
        as[mi] = __builtin_amdgcn_mfma_f32_16x16x32_bf16(ak, bq[ks], as[mi], 0, 0, 0);
      }
    }

    float rmax = as[0][0];
#pragma unroll
    for (int mi = 0; mi < 4; ++mi) {
#pragma unroll
      for (int r = 0; r < 4; ++r) rmax = fmaxf(rmax, as[mi][r]);
    }
    rmax = fmaxf(rmax, __shfl_xor(rmax, 16));
    rmax = fmaxf(rmax, __shfl_xor(rmax, 32));
    const float mn = fmaxf(m, rmax);
    const float sc = __expf(m - mn);
    float p[4][4];
    float rsum = 0.f;
#pragma unroll
    for (int mi = 0; mi < 4; ++mi) {
#pragma unroll
      for (int r = 0; r < 4; ++r) { p[mi][r] = __expf(as[mi][r] - mn); rsum += p[mi][r]; }
    }
    rsum += __shfl_xor(rsum, 16);
    rsum += __shfl_xor(rsum, 32);
    l = l * sc + rsum;
    m = mn;
#pragma unroll
    for (int mi = 0; mi < 4; ++mi) {
#pragma unroll
      for (int r = 0; r < 4; ++r) po[mi][r] *= sc;
    }
#pragma unroll
    for (int mi = 0; mi < 4; ++mi) {
      s16x4 pk;
#pragma unroll
      for (int r = 0; r < 4; ++r) pk[r] = f2bfs(p[mi][r]);
      *(s16x4*)&sP[w][lr * 64 + ((mi ^ (lr & 3)) * 16 + kg * 4)] = pk;
    }
#pragma unroll
    for (int ks = 0; ks < 2; ++ks) {
      short8 bp = *(const short8*)&sP[w][lr * 64 + (((ks * 2 + (kg >> 1)) ^ (lr & 3)) * 16 + (kg & 1) * 8)];
#pragma unroll
      for (int mi = 0; mi < 4; ++mi) {
        short8 av = *(const short8*)&sV[(mi * 16 + lr) * 64 + ((ks * 4 + kg) ^ (lr & 7)) * 8];
        po[mi] = __builtin_amdgcn_mfma_f32_16x16x32_bf16(av, bp, po[mi], 0, 0, 0);
      }
    }
    __syncthreads();
  }

  const float inv = 1.f / l;
  const int t2 = q0 + w * 16 + lr;
  const int n = h * 1024 + t2;
  short* ob = out + ((long)b * 1024 + (n >> 3)) * 512 + (n & 7) * 64;
#pragma unroll
  for (int mi = 0; mi < 4; ++mi) {
    s16x4 o;
#pragma unroll
    for (int r = 0; r < 4; ++r) o[r] = f2bfs(po[mi][r] * inv);
    *(s16x4*)&ob[mi * 16 + kg * 4] = o;
  }
}

// ---------------------------------------------------------------------------
// Sum TWO conv split-K partials -> z bf16, accumulate BN sum/sumsq stats.
// ---------------------------------------------------------------------------
__global__ __launch_bounds__(256) void reduce_bn(
    const float* __restrict__ parts, long pstride,
    short* __restrict__ z, float* stats)
{
  const int r0 = blockIdx.x * 16;
  const int c = threadIdx.x * 2;
  float s0 = 0.f, s1 = 0.f, q0 = 0.f, q1 = 0.f;
#pragma unroll 4
  for (int r = 0; r < 16; ++r) {
    const long idx = (long)(r0 + r) * 512 + c;
    float a0 = parts[idx] + parts[idx + pstride];
    float a1 = parts[idx + 1] + parts[idx + 1 + pstride];
    z[idx] = f2bfs(a0); z[idx + 1] = f2bfs(a1);
    s0 += a0; s1 += a1; q0 += a0 * a0; q1 += a1 * a1;
  }
  atomicAdd(&stats[c], s0);
  atomicAdd(&stats[c + 1], s1);
  atomicAdd(&stats[512 + c], q0);
  atomicAdd(&stats[512 + c + 1], q1);
}

// ---------------------------------------------------------------------------
// LayerNorm rows of 512 (fp32 in), one wave per row (4 rows/block).
// ---------------------------------------------------------------------------
template<int ADDPE, int OUTF32>
__global__ __launch_bounds__(256) void ln_rows(
    const float* __restrict__ X, const float* __restrict__ g, const float* __restrict__ b,
    const float* __restrict__ pe, void* __restrict__ Y)
{
  const int row = blockIdx.x * 4 + (threadIdx.x >> 6);
  const int lane = threadIdx.x & 63;
  const int c0 = lane * 8;
  const float* src = X + (long)row * 512 + c0;
  f32x4 a = *(const f32x4*)src, c = *(const f32x4*)(src + 4);
  float x[8] = {a[0], a[1], a[2], a[3], c[0], c[1], c[2], c[3]};
  float s = 0.f, q = 0.f;
#pragma unroll
  for (int j = 0; j < 8; ++j) { s += x[j]; q += x[j] * x[j]; }
#pragma unroll
  for (int off = 32; off > 0; off >>= 1) { s += __shfl_xor(s, off); q += __shfl_xor(q, off); }
  const float mean = s * (1.f / 512.f);
  const float var = q * (1.f / 512.f) - mean * mean;
  const float rstd = rsqrtf(var + 1e-5f);
  f32x4 g0 = *(const f32x4*)(g + c0), g1 = *(const f32x4*)(g + c0 + 4);
  f32x4 b0 = *(const f32x4*)(b + c0), b1 = *(const f32x4*)(b + c0 + 4);
  float gg[8] = {g0[0], g0[1], g0[2], g0[3], g1[0], g1[1], g1[2], g1[3]};
  float bb[8] = {b0[0], b0[1], b0[2], b0[3], b1[0], b1[1], b1[2], b1[3]};
  float y[8];
#pragma unroll
  for (int j = 0; j < 8; ++j) {
    y[j] = (x[j] - mean) * rstd * gg[j] + bb[j];
    if (ADDPE) y[j] += pe[(long)(row & 1023) * 512 + c0 + j];
  }
  if (OUTF32) {
    float* dst = (float*)Y + (long)row * 512 + c0;
    *(f32x4*)dst = (f32x4){y[0], y[1], y[2], y[3]};
    *(f32x4*)(dst + 4) = (f32x4){y[4], y[5], y[6], y[7]};
  } else {
    short8 o;
#pragma unroll
    for (int j = 0; j < 8; ++j) o[j] = f2bfs(y[j]);
    *(short8*)((short*)Y + (long)row * 512 + c0) = o;
  }
}

// ---------------------------------------------------------------------------
// 64x64-tile transpose -> bf16 out. INF32: fp32 input (weights) or bf16 input.
// ---------------------------------------------------------------------------
template<int INF32>
__global__ __launch_bounds__(256) void transpose64(
    const void* __restrict__ in_, int ldin, short* __restrict__ out, int ldout,
    int ctiles, int zshift, long zh_in, long zl_in, long z_out)
{
  __shared__ short t[64][72];
  const int z = blockIdx.z;
  const long inoff = (long)(z >> zshift) * zh_in + (long)(z & ((1 << zshift) - 1)) * zl_in;
  const int tr = blockIdx.x / ctiles, tc = blockIdx.x % ctiles;
  short* dst = out + (long)z * z_out + (long)(tc * 64) * ldout + tr * 64;
  const int tid = threadIdx.x;
#pragma unroll
  for (int p = 0; p < 2; ++p) {
    int idx = p * 256 + tid;
    int r = idx >> 3, c8 = (idx & 7) * 8;
    if (INF32) {
      const float* src = (const float*)in_ + inoff + (long)(tr * 64 + r) * ldin + tc * 64 + c8;
      f32x4 v0 = *(const f32x4*)src, v1 = *(const f32x4*)(src + 4);
#pragma unroll
      for (int j = 0; j < 4; ++j) { t[r][c8 + j] = f2bfs(v0[j]); t[r][c8 + 4 + j] = f2bfs(v1[j]); }
    } else {
      const short* src = (const short*)in_ + inoff + (long)(tr * 64 + r) * ldin + tc * 64 + c8;
      short8 v = *(const short8*)src;
#pragma unroll
      for (int j = 0; j < 8; ++j) t[r][c8 + j] = v[j];
    }
  }
  __syncthreads();
#pragma unroll
  for (int p = 0; p < 2; ++p) {
    int idx = p * 256 + tid;
    int c = idx >> 3, r8 = (idx & 7) * 8;
    short8 v;
#pragma unroll
    for (int j = 0; j < 8; ++j) v[j] = t[r8 + j][c];
    *(short8*)(dst + (long)c * ldout + r8) = v;
  }
}

// wdP fragment-packed, 32 taps (tap 31 pre-zeroed): value wd[e][i][KK] ->
// wdP[((e>>4)*512 + KK*16 + (i>>5))*512 + ((i>>3)&3)*128 + (e&15)*8 + (i&7)]
__global__ __launch_bounds__(256) void wd_pack(const float* __restrict__ wd, short* __restrict__ wdP)
{
  const int gid = blockIdx.x * 256 + threadIdx.x;  // 262144 = 512*512
  const int e = gid >> 9, i = gid & 511;
  const float* src = wd + ((long)e * 512 + i) * 31;
  const long rowtile = (long)(e >> 4) * (512L * 512);
  const int inner = ((i >> 3) & 3) * 128 + (e & 15) * 8 + (i & 7);
#pragma unroll
  for (int KK = 0; KK < 31; ++KK)
    wdP[rowtile + (long)(KK * 16 + (i >> 5)) * 512 + inner] = f2bfs(src[KK]);
}

// pe[t][2p] = sin(t * 10000^(-p/256)), pe[t][2p+1] = cos(...)
__global__ __launch_bounds__(256) void pe_init(float* __restrict__ pe)
{
  const int gid = blockIdx.x * 256 + threadIdx.x;  // 262144 = 1024*256
  const int t = gid >> 8, p = gid & 255;
  const float freq = __expf(-(float)p * (9.210340371976184f / 256.f));
  const float ang = (float)t * freq;
  pe[(long)t * 512 + 2 * p]     = sinf(ang);
  pe[(long)t * 512 + 2 * p + 1] = cosf(ang);
}

// glu = a * sigmoid(g) from y1[N][1024] fp32 -> glu_pad[b][16+t][512] bf16
__global__ __launch_bounds__(256) void glu_kernel(const float* __restrict__ y1, short* __restrict__ gp)
{
  const int gid = blockIdx.x * 256 + threadIdx.x;  // 1048576
  const int row = gid >> 7;
  const int ci = (gid & 127) * 4;
  const float* base = y1 + (long)row * 1024;
  f32x4 a = *(const f32x4*)(base + ci);
  f32x4 g = *(const f32x4*)(base + 512 + ci);
  const int b = row >> 10, t = row & 1023;
  s16x4 o;
#pragma unroll
  for (int j = 0; j < 4; ++j) o[j] = f2bfs(a[j] * sigmoidf_(g[j]));
  *(s16x4*)(gp + ((long)b * 1056 + 16 + t) * 512 + ci) = o;
}

__global__ void bn_stats(float* stats, const float* __restrict__ bn_g, const float* __restrict__ bn_b)
{
  const int c = blockIdx.x * 256 + threadIdx.x;
  if (c < 512) {
    float mean = stats[c] * (1.f / 8192.f);
    float var = stats[512 + c] * (1.f / 8192.f) - mean * mean;
    float sc = bn_g[c] * rsqrtf(var + 1e-5f);
    stats[1024 + c] = sc;
    stats[1536 + c] = bn_b[c] - mean * sc;
  }
}

__global__ __launch_bounds__(256) void bn_silu(const short* __restrict__ z, const float* __restrict__ stats,
                                               short* __restrict__ out)
{
  const long base = ((long)blockIdx.x * 256 + threadIdx.x) * 8;
  const int c0 = (int)(base & 511);
  short8 v = *(const short8*)(z + base);
  short8 o;
#pragma unroll
  for (int j = 0; j < 8; ++j) {
    const int c = c0 + j;
    float y = bfs2f(v[j]) * stats[1024 + c] + stats[1536 + c];
    o[j] = f2bfs(y * sigmoidf_(y));
  }
  *(short8*)(out + base) = o;
}

// plain elementwise fp32 -> bf16 cast (grid-stride)
__global__ __launch_bounds__(256) void cast_bf16(const float* __restrict__ in, short* __restrict__ out, long n)
{
  for (long i = (long)blockIdx.x * 256 + threadIdx.x; i < n; i += (long)gridDim.x * 256)
    out[i] = f2bfs(in[i]);
}

// ---------------------------------------------------------------------------
extern "C" void kernel_launch(void* const* d_in, const int* in_sizes, int n_in,
                              void* d_out, int out_size, void* d_ws, size_t ws_size,
                              hipStream_t stream)
{
  (void)in_sizes; (void)n_in; (void)out_size; (void)ws_size;
  const float* x_in   = (const float*)d_in[0];
  const float* ff1_g  = (const float*)d_in[1];
  const float* ff1_bb = (const float*)d_in[2];
  const float* ff1_w1 = (const float*)d_in[3];
  const float* ff1_b1 = (const float*)d_in[4];
  const float* ff1_w2 = (const float*)d_in[5];
  const float* ff1_b2 = (const float*)d_in[6];
  const float* mha_g  = (const float*)d_in[7];
  const float* mha_b  = (const float*)d_in[8];
  const float* wq     = (const float*)d_in[9];
  const float* bq     = (const float*)d_in[10];
  const float* wk     = (const float*)d_in[11];
  const float* bk     = (const float*)d_in[12];
  const float* wv     = (const float*)d_in[13];
  const float* bv     = (const float*)d_in[14];
  const float* wo     = (const float*)d_in[15];
  const float* bo     = (const float*)d_in[16];
  const float* cv_g   = (const float*)d_in[17];
  const float* cv_b   = (const float*)d_in[18];
  const float* cv_w1  = (const float*)d_in[19];
  const float* cv_b1  = (const float*)d_in[20];
  const float* cv_wd  = (const float*)d_in[21];
  const float* bn_g   = (const float*)d_in[22];
  const float* bn_b   = (const float*)d_in[23];
  const float* cv_w2  = (const float*)d_in[24];
  const float* cv_b2  = (const float*)d_in[25];
  const float* ff2_g  = (const float*)d_in[26];
  const float* ff2_b  = (const float*)d_in[27];
  const float* ff2_w1 = (const float*)d_in[28];
  const float* ff2_b1 = (const float*)d_in[29];
  const float* ff2_w2 = (const float*)d_in[30];
  const float* ff2_b2 = (const float*)d_in[31];
  const float* fin_g  = (const float*)d_in[32];
  const float* fin_b  = (const float*)d_in[33];

  size_t off = 0;
  char* wsb = (char*)d_ws;
  auto take = [&](size_t n) { char* p = wsb + off; off += (n + 255) & ~(size_t)255; return p; };
  short* ff1w1T = (short*)take(2048L * 512 * 2);
  short* ff1w2T = (short*)take(512L * 2048 * 2);
  short* qkvT   = (short*)take(1536L * 512 * 2);
  short* woT    = (short*)take(512L * 512 * 2);
  short* cw1b   = (short*)take(1024L * 512 * 2);
  short* cw2b   = (short*)take(512L * 512 * 2);
  short* wdP    = (short*)take(32L * 512 * 512 * 2);   // 32 taps (tap 31 zero)
  short* ff2w1T = (short*)take(2048L * 512 * 2);
  short* ff2w2T = (short*)take(512L * 2048 * 2);
  float* xcur   = (float*)take(8192L * 512 * 4);
  char*  Ra     = take(8192L * 2048 * 2);              // hid bf16 / qkv bf16 / y1 fp32
  short* Rb     = (short*)take(8192L * 512 * 2);       // ln out / att_o / conv z
  short* Rg     = (short*)take((8L * 1056 + 2) * 512 * 2); // glu_pad (+slack rows)
  char*  Rshare = take(2L * 8192 * 512 * 4);           // conv partials x2 (32MB)
  short* vt     = (short*)take(64L * 64 * 1024 * 2);   // V^T per (b,h)
  float* pe     = (float*)take(1024L * 512 * 4);
  float* stats  = (float*)take(2048L * 4);

  short* hid = (short*)Ra;
  short* qkv = (short*)Ra;
  float* y1  = (float*)Ra;
  float* part0 = (float*)Rshare;

  // ---- weight packs (fp32 -> bf16; per call) ----
  transpose64<1><<<dim3(256, 1, 1), 256, 0, stream>>>(ff1_w1, 2048, ff1w1T, 512, 32, 0, 0, 0, 0);
  transpose64<1><<<dim3(256, 1, 1), 256, 0, stream>>>(ff1_w2, 512, ff1w2T, 2048, 8, 0, 0, 0, 0);
  transpose64<1><<<dim3(8, 1, 8), 256, 0, stream>>>(wq, 64, qkvT, 512, 1, 0, 32768, 0, 32768);
  transpose64<1><<<dim3(8, 1, 8), 256, 0, stream>>>(wk, 64, qkvT + 512 * 512, 512, 1, 0, 32768, 0, 32768);
  transpose64<1><<<dim3(8, 1, 8), 256, 0, stream>>>(wv, 64, qkvT + 1024 * 512, 512, 1, 0, 32768, 0, 32768);
  transpose64<1><<<dim3(64, 1, 1), 256, 0, stream>>>(wo, 512, woT, 512, 8, 0, 0, 0, 0);
  transpose64<1><<<dim3(256, 1, 1), 256, 0, stream>>>(ff2_w1, 2048, ff2w1T, 512, 32, 0, 0, 0, 0);
  transpose64<1><<<dim3(256, 1, 1), 256, 0, stream>>>(ff2_w2, 512, ff2w2T, 2048, 8, 0, 0, 0, 0);
  (void)hipMemsetAsync(wdP, 0, 32L * 512 * 512 * 2, stream);   // zero tap 31
  wd_pack<<<1024, 256, 0, stream>>>(cv_wd, wdP);
  pe_init<<<1024, 256, 0, stream>>>(pe);
  cast_bf16<<<2048, 256, 0, stream>>>(cv_w1, cw1b, 524288L);
  cast_bf16<<<1024, 256, 0, stream>>>(cv_w2, cw2b, 262144L);

  // ---- FF1: x1 = 1.5 x + 0.5 (silu(ln(x) W1 + b1) W2 + b2) ----
  ln_rows<0, 0><<<2048, 256, 0, stream>>>(x_in, ff1_g, ff1_bb, nullptr, Rb);
  gemm_bt<128, 128, 2, 2, EPI_SILU><<<dim3(64, 16, 1), 256, 0, stream>>>(
      Rb, 512, 0, 0, ff1w1T, 512, 0, 0, 512, 0,
      hid, 2048, 0, 0, 0, ff1_b1, nullptr, nullptr, nullptr, 0.f, 0.f);
  gemm_bt<64, 64, 2, 2, EPI_RES><<<dim3(128, 8, 1), 256, 0, stream>>>(
      hid, 2048, 0, 0, ff1w2T, 2048, 0, 0, 2048, 0,
      xcur, 512, 0, 0, 0, ff1_b2, nullptr, nullptr, x_in, 1.5f, 0.5f);

  // ---- MHSA: x2 = 2 x1 + (scramble(attn) Wo + bo) ----
  ln_rows<1, 0><<<2048, 256, 0, stream>>>(xcur, mha_g, mha_b, pe, Rb);
  gemm_bt<128, 128, 2, 2, EPI_QKV><<<dim3(64, 12, 1), 256, 0, stream>>>(
      Rb, 512, 0, 0, qkvT, 512, 0, 0, 512, 0,
      qkv, 1536, 0, 0, 0, bq, bk, bv, nullptr, 0.f, 0.f);
  transpose64<0><<<dim3(16, 1, 64), 256, 0, stream>>>(qkv + 1024, 1536, vt, 1024, 1, 3,
                                                      1024L * 1536, 64, 65536);
  flash_attn<<<dim3(16, 1, 64), 256, 0, stream>>>(qkv, vt, Rb);
  gemm_bt<64, 64, 2, 2, EPI_RES><<<dim3(128, 8, 1), 256, 0, stream>>>(
      Rb, 512, 0, 0, woT, 512, 0, 0, 512, 0,
      xcur, 512, 0, 0, 0, bo, nullptr, nullptr, xcur, 2.f, 1.f);

  // ---- Conv module: x3 = 2 x2 + (W2 silu(BN(conv(glu(W1 ln(x2) + b1)))) + b2) ----
  ln_rows<0, 0><<<2048, 256, 0, stream>>>(xcur, cv_g, cv_b, nullptr, Rb);
  gemm_bt<128, 128, 2, 2, EPI_F32BIAS><<<dim3(64, 8, 1), 256, 0, stream>>>(
      Rb, 512, 0, 0, cw1b, 512, 0, 0, 512, 0,
      y1, 1024, 0, 0, 0, cv_b1, nullptr, nullptr, nullptr, 0.f, 0.f);
  (void)hipMemsetAsync(Rg, 0, (8L * 1056 + 2) * 512 * 2, stream);
  glu_kernel<<<4096, 256, 0, stream>>>(y1, Rg);
  (void)hipMemsetAsync(stats, 0, 1024 * sizeof(float), stream);
  conv_tap<<<512, 256, 0, stream>>>(Rg, wdP, part0);
  reduce_bn<<<512, 256, 0, stream>>>(part0, 8192L * 512, Rb, stats);
  bn_stats<<<2, 256, 0, stream>>>(stats, bn_g, bn_b);
  bn_silu<<<2048, 256, 0, stream>>>(Rb, stats, (short*)Rg);
  gemm_bt<64, 64, 2, 2, EPI_RES><<<dim3(128, 8, 1), 256, 0, stream>>>(
      (short*)Rg, 512, 0, 0, cw2b, 512, 0, 0, 512, 0,
      xcur, 512, 0, 0, 0, cv_b2, nullptr, nullptr, xcur, 2.f, 1.f);

  // ---- FF2: x4 = 1.5 x3 + 0.5 (...) ----
  ln_rows<0, 0><<<2048, 256, 0, stream>>>(xcur, ff2_g, ff2_b, nullptr, Rb);
  gemm_bt<128, 128, 2, 2, EPI_SILU><<<dim3(64, 16, 1), 256, 0, stream>>>(
      Rb, 512, 0, 0, ff2w1T, 512, 0, 0, 512, 0,
      hid, 2048, 0, 0, 0, ff2_b1, nullptr, nullptr, nullptr, 0.f, 0.f);
  gemm_bt<64, 64, 2, 2, EPI_RES><<<dim3(128, 8, 1), 256, 0, stream>>>(
      hid, 2048, 0, 0, ff2w2T, 2048, 0, 0, 2048, 0,
      xcur, 512, 0, 0, 0, ff2_b2, nullptr, nullptr, xcur, 1.5f, 0.5f);

  // ---- final LN -> d_out (fp32) ----
  ln_rows<0, 1><<<2048, 256, 0, stream>>>(xcur, fin_g, fin_b, nullptr, (float*)d_out);
}